// Round 5
// baseline (390.868 us; speedup 1.0000x reference)
//
#include <hip/hip_runtime.h>
#include <cstdint>
#include <cstddef>

// ---------------------------------------------------------------------------
// MultiHeadAttention: B=4, T=2048, D=1024, H=16, DH=64
// Round 5: (1) qkv GEMM stages A directly from f32 inputs (VGPR cvt +
// ds_write_b128) — the big cast pass shrinks to weights-only. (2) attention
// Q-tile 256 (4 waves x 64 q rows, 256 blocks = 1/CU) halving LDS read
// volume per unit compute. XCD remap + conflict-free swizzles kept from R4.
// ---------------------------------------------------------------------------

typedef float f32x4 __attribute__((ext_vector_type(4)));
typedef short bf16x8 __attribute__((ext_vector_type(8)));
typedef float fltx4 __attribute__((ext_vector_type(4)));
typedef unsigned short u16x4 __attribute__((ext_vector_type(4)));

#define GLOBAL_AS __attribute__((address_space(1)))
#define LDS_AS __attribute__((address_space(3)))

__device__ __forceinline__ unsigned short f2bf(float f) {
    union { float f; unsigned int u; } x;
    x.f = f;
    unsigned int u = x.u;
    unsigned int r = (u + 0x7FFFu + ((u >> 16) & 1u)) >> 16;  // RNE
    return (unsigned short)r;
}

__device__ __forceinline__ unsigned int pack_trunc(float a, float b) {
    union { float f; unsigned int u; } x, y;
    x.f = a; y.f = b;
    return (x.u >> 16) | (y.u & 0xFFFF0000u);  // bf16 trunc; rel err < 2^-8
}

__device__ __forceinline__ unsigned int pack_rh(float a, float b) {
    // round-half-up bf16 pack (cheap, bias only on exact ties)
    union { float f; unsigned int u; } x, y;
    x.f = a; y.f = b;
    return ((x.u + 0x8000u) >> 16) | ((y.u + 0x8000u) & 0xFFFF0000u);
}

// ---------------------------------------------------------------------------
// Cast kernel (weights only now): wq,wk,wv,wo (1M each) f32 -> bf16.
// ---------------------------------------------------------------------------
__global__ __launch_bounds__(256) void cast_w_kernel(
    const float* __restrict__ wq, const float* __restrict__ wk,
    const float* __restrict__ wv, const float* __restrict__ wo,
    unsigned short* __restrict__ dst)
{
    const size_t WSEG = 1048576;  // D*D
    size_t i = ((size_t)blockIdx.x * 256 + threadIdx.x) * 4;
    const float* src;
    size_t off;
    if (i < WSEG)          { src = wq; off = i; }
    else if (i < 2 * WSEG) { src = wk; off = i - WSEG; }
    else if (i < 3 * WSEG) { src = wv; off = i - 2 * WSEG; }
    else                   { src = wo; off = i - 3 * WSEG; }
    fltx4 val = *(const fltx4*)(src + off);
    u16x4 o;
    o[0] = f2bf(val[0]);
    o[1] = f2bf(val[1]);
    o[2] = f2bf(val[2]);
    o[3] = f2bf(val[3]);
    *(u16x4*)(dst + i) = o;
}

// ---------------------------------------------------------------------------
// Fused QKV GEMM with in-kernel A cast: z selects {q,k,v} f32 source.
// A staged f32->bf16 via VGPR (round-half-up) + ds_write_b128 w/ swizzle;
// W staged via global_load_lds. XCD remap: lin&7 owns a 1024-row A band.
// z<2 -> bf16 out [B,H,T,DH] (*scale for z==0); z==2 -> bf16 out [B,H,DH,T].
// ---------------------------------------------------------------------------
__global__ __launch_bounds__(256) void qkv_gemm_kernel(
    const float* __restrict__ qx, const float* __restrict__ kx,
    const float* __restrict__ vx,
    const unsigned short* __restrict__ Wc,   // wqc base; wkc=+1M, wvc=+2M
    const float* __restrict__ bq, const float* __restrict__ bk,
    const float* __restrict__ bv,
    unsigned short* __restrict__ Outs,       // Qhp base; Khp=+8M, Vtp=+16M
    float qscale)
{
    const int z = blockIdx.z;
    const float* A32 = (z == 0) ? qx : (z == 1) ? kx : vx;
    const unsigned short* Bw = Wc + (size_t)z * 1048576;
    const float* bias = (z == 0) ? bq : (z == 1) ? bk : bv;
    unsigned short* outp = Outs + (size_t)z * 8388608;
    const float scale = (z == 0) ? qscale : 1.0f;
    const bool vmode = (z == 2);

    __shared__ __align__(16) unsigned short lA[128 * 32];
    __shared__ __align__(16) unsigned short lB[128 * 32];
    const int tid = threadIdx.x;
    const int w = tid >> 6, lane = tid & 63;
    const int quad = lane >> 4, l16 = lane & 15;

    // XCD-locality remap
    const int lin = blockIdx.x + (blockIdx.y << 3);
    const int r_ = lin & 7, s_ = lin >> 3;
    const int bm = ((r_ << 3) | (s_ & 7)) * 128;
    const int bn = (s_ >> 3) * 128;

    const int wm = (w >> 1) * 64, wn = (w & 1) * 64;

    f32x4 acc[4][4] = {};
    const int srow0 = w * 16 + (lane >> 2);
    const int gc = lane & 3;

    for (int kb = 0; kb < 32; ++kb) {
        const unsigned short* Bb = Bw + (size_t)bn * 1024 + kb * 32;
#pragma unroll
        for (int i = 0; i < 2; ++i) {
            int row = i * 64 + srow0;
            // A: f32 global -> bf16 LDS (swizzled position = gc ^ ((row>>1)&3))
            const float* src = A32 + (size_t)(bm + row) * 1024 + kb * 32 + gc * 8;
            fltx4 v0 = *(const fltx4*)(src);
            fltx4 v1 = *(const fltx4*)(src + 4);
            uint4 pk;
            pk.x = pack_rh(v0[0], v0[1]);
            pk.y = pack_rh(v0[2], v0[3]);
            pk.z = pack_rh(v1[0], v1[1]);
            pk.w = pack_rh(v1[2], v1[3]);
            *(uint4*)(lA + row * 32 + (gc ^ ((row >> 1) & 3)) * 8) = pk;
            // B: bf16 weights via DMA (same swizzle baked into source chunk)
            int gcb = gc ^ ((row >> 1) & 3);
            __builtin_amdgcn_global_load_lds(
                (const GLOBAL_AS unsigned int*)(Bb + (size_t)row * 1024 + gcb * 8),
                (LDS_AS unsigned int*)(lB + i * 2048 + w * 512), 16, 0, 0);
        }
        __syncthreads();

        bf16x8 af[4], bfr[4];
#pragma unroll
        for (int mi = 0; mi < 4; ++mi) {
            int row = wm + mi * 16 + l16;
            af[mi] = *(const bf16x8*)(lA + row * 32 + ((quad ^ ((row >> 1) & 3)) * 8));
        }
#pragma unroll
        for (int ni = 0; ni < 4; ++ni) {
            int row = wn + ni * 16 + l16;
            bfr[ni] = *(const bf16x8*)(lB + row * 32 + ((quad ^ ((row >> 1) & 3)) * 8));
        }
#pragma unroll
        for (int mi = 0; mi < 4; ++mi)
#pragma unroll
            for (int ni = 0; ni < 4; ++ni)
                acc[mi][ni] = __builtin_amdgcn_mfma_f32_16x16x32_bf16(af[mi], bfr[ni], acc[mi][ni], 0, 0, 0);
        __syncthreads();
    }

#pragma unroll
    for (int mi = 0; mi < 4; ++mi) {
        int rowb = bm + wm + mi * 16 + quad * 4;
#pragma unroll
        for (int ni = 0; ni < 4; ++ni) {
            int col = bn + wn + ni * 16 + l16;
            float bv_ = bias[col];
#pragma unroll
            for (int r = 0; r < 4; ++r) {
                int m = rowb + r;
                float vout = (acc[mi][ni][r] + bv_) * scale;
                int b = m >> 11, t = m & 2047, h = col >> 6, d = col & 63;
                if (!vmode) {
                    outp[((size_t)(b * 16 + h) * 2048 + t) * 64 + d] = f2bf(vout);
                } else {
                    outp[((size_t)(b * 16 + h) * 64 + d) * 2048 + t] = f2bf(vout);
                }
            }
        }
    }
}

// ---------------------------------------------------------------------------
// Output-projection GEMM (f32 out), XCD remap + swizzle (unchanged from R4).
// ---------------------------------------------------------------------------
__global__ __launch_bounds__(256) void out_gemm_kernel(
    const unsigned short* __restrict__ A,
    const unsigned short* __restrict__ Bw,
    const float* __restrict__ bias,
    float* __restrict__ outp)
{
    __shared__ __align__(16) unsigned short lA[128 * 32];
    __shared__ __align__(16) unsigned short lB[128 * 32];
    const int tid = threadIdx.x;
    const int w = tid >> 6, lane = tid & 63;
    const int quad = lane >> 4, l16 = lane & 15;

    const int lin = blockIdx.x + (blockIdx.y << 3);
    const int r_ = lin & 7, s_ = lin >> 3;
    const int bm = ((r_ << 3) | (s_ & 7)) * 128;
    const int bn = (s_ >> 3) * 128;

    const int wm = (w >> 1) * 64, wn = (w & 1) * 64;

    f32x4 acc[4][4] = {};
    const int srow0 = w * 16 + (lane >> 2);

    for (int kb = 0; kb < 32; ++kb) {
        const unsigned short* Ab = A + (size_t)bm * 1024 + kb * 32;
        const unsigned short* Bb = Bw + (size_t)bn * 1024 + kb * 32;
#pragma unroll
        for (int i = 0; i < 2; ++i) {
            int row = i * 64 + srow0;
            int gcb = (lane & 3) ^ ((row >> 1) & 3);
            __builtin_amdgcn_global_load_lds(
                (const GLOBAL_AS unsigned int*)(Ab + (size_t)row * 1024 + gcb * 8),
                (LDS_AS unsigned int*)(lA + i * 2048 + w * 512), 16, 0, 0);
            __builtin_amdgcn_global_load_lds(
                (const GLOBAL_AS unsigned int*)(Bb + (size_t)row * 1024 + gcb * 8),
                (LDS_AS unsigned int*)(lB + i * 2048 + w * 512), 16, 0, 0);
        }
        __syncthreads();

        bf16x8 af[4], bfr[4];
#pragma unroll
        for (int mi = 0; mi < 4; ++mi) {
            int row = wm + mi * 16 + l16;
            af[mi] = *(const bf16x8*)(lA + row * 32 + ((quad ^ ((row >> 1) & 3)) * 8));
        }
#pragma unroll
        for (int ni = 0; ni < 4; ++ni) {
            int row = wn + ni * 16 + l16;
            bfr[ni] = *(const bf16x8*)(lB + row * 32 + ((quad ^ ((row >> 1) & 3)) * 8));
        }
#pragma unroll
        for (int mi = 0; mi < 4; ++mi)
#pragma unroll
            for (int ni = 0; ni < 4; ++ni)
                acc[mi][ni] = __builtin_amdgcn_mfma_f32_16x16x32_bf16(af[mi], bfr[ni], acc[mi][ni], 0, 0, 0);
        __syncthreads();
    }

#pragma unroll
    for (int mi = 0; mi < 4; ++mi) {
        int rowb = bm + wm + mi * 16 + quad * 4;
#pragma unroll
        for (int ni = 0; ni < 4; ++ni) {
            int col = bn + wn + ni * 16 + l16;
            float bv_ = bias[col];
#pragma unroll
            for (int r = 0; r < 4; ++r)
                outp[(size_t)(rowb + r) * 1024 + col] = acc[mi][ni][r] + bv_;
        }
    }
}

// ---------------------------------------------------------------------------
// Flash attention v4: Q-tile 256 (4 waves x 64 q rows), K-tiles of 64,
// double-buffered LDS staging, m=0 softmax, paired qblks (7-y, y) -> uniform
// 36 K-steps/block. Grid (64 bh, 4) = 256 blocks = 1/CU; bh&7 = XCD.
// ---------------------------------------------------------------------------
__global__ __launch_bounds__(256, 1) void attn_kernel(
    const unsigned short* __restrict__ Qh,
    const unsigned short* __restrict__ Kh,
    const unsigned short* __restrict__ Vt,
    unsigned short* __restrict__ att)
{
    const int tid = threadIdx.x;
    const int w = tid >> 6, lane = tid & 63;
    const int qd = lane >> 4, l16 = lane & 15;
    const int bh = blockIdx.x;    // 0..63 (bh&7 = XCD)
    const int pairy = blockIdx.y; // 0..3

    const unsigned short* Qp = Qh + (size_t)bh * 2048 * 64;
    const unsigned short* Kp = Kh + (size_t)bh * 2048 * 64;
    const unsigned short* Vp = Vt + (size_t)bh * 64 * 2048;
    const int b = bh >> 4, h = bh & 15;

    __shared__ __align__(16) unsigned short Kl[2][64 * 64];   // 16 KB
    __shared__ __align__(16) unsigned short Vl[2][64 * 64];   // 16 KB
    __shared__ __align__(16) unsigned short Pl[4][4][16 * 64]; // 32 KB

    auto stage = [&](int kt, int buf) {
#pragma unroll
        for (int j = 0; j < 2; ++j) {
            int r = w * 16 + j * 8 + (lane >> 3);
            int c = (lane & 7) ^ (r & 7);
            __builtin_amdgcn_global_load_lds(
                (const GLOBAL_AS unsigned int*)(Kp + (size_t)(kt * 64 + r) * 64 + c * 8),
                (LDS_AS unsigned int*)(&Kl[buf][(w * 16 + j * 8) * 64]), 16, 0, 0);
            __builtin_amdgcn_global_load_lds(
                (const GLOBAL_AS unsigned int*)(Vp + (size_t)r * 2048 + kt * 64 + c * 8),
                (LDS_AS unsigned int*)(&Vl[buf][(w * 16 + j * 8) * 64]), 16, 0, 0);
        }
    };

    auto run_phase = [&](int qblk) {  // qblk in 0..7, 256 q rows
        const int wqbase = qblk * 256 + w * 64;
        const int ktmax = 4 * qblk + 3;

        // Q fragments (B-operand: l16 = q row, qd*8+j = dh); 4 subtiles
        bf16x8 qa[4][2];
#pragma unroll
        for (int qt = 0; qt < 4; ++qt)
#pragma unroll
            for (int ks = 0; ks < 2; ++ks)
                qa[qt][ks] = *(const bf16x8*)(Qp + (size_t)(wqbase + qt * 16 + l16) * 64 + ks * 32 + qd * 8);

        float lp[4] = {0.0f, 0.0f, 0.0f, 0.0f};
        f32x4 O[4][4] = {};

        __syncthreads();  // prior phase's LDS reads complete before restaging
        stage(0, 0);

        for (int kt = 0; kt <= ktmax; ++kt) {
            __syncthreads();  // implicit vmcnt(0): buf[kt&1] staged
            if (kt < ktmax) stage(kt + 1, (kt + 1) & 1);

            if (kt * 64 <= wqbase + 63) {  // wave-uniform skip of masked tiles
                const unsigned short* kl = &Kl[kt & 1][0];
                const unsigned short* vl = &Vl[kt & 1][0];

                // K fragments (A-operand: l16 = k row, qd*8+j = dh)
                bf16x8 kf[4][2];
#pragma unroll
                for (int nt = 0; nt < 4; ++nt)
#pragma unroll
                    for (int ks = 0; ks < 2; ++ks)
                        kf[nt][ks] = *(const bf16x8*)(kl + (nt * 16 + l16) * 64 +
                                                      (((ks * 4 + qd) ^ (l16 & 7)) * 8));

                // S^T = K Q^T
                f32x4 S[4][4];
#pragma unroll
                for (int qt = 0; qt < 4; ++qt)
#pragma unroll
                    for (int nt = 0; nt < 4; ++nt) {
                        f32x4 a = {};
                        a = __builtin_amdgcn_mfma_f32_16x16x32_bf16(kf[nt][0], qa[qt][0], a, 0, 0, 0);
                        a = __builtin_amdgcn_mfma_f32_16x16x32_bf16(kf[nt][1], qa[qt][1], a, 0, 0, 0);
                        S[qt][nt] = a;
                    }

                // causal mask (diagonal region only)
                if (kt * 64 + 63 > wqbase) {
#pragma unroll
                    for (int qt = 0; qt < 4; ++qt) {
                        int qrow = wqbase + qt * 16 + l16;
#pragma unroll
                        for (int nt = 0; nt < 4; ++nt) {
                            int kbase = kt * 64 + nt * 16 + qd * 4;
#pragma unroll
                            for (int r = 0; r < 4; ++r)
                                if (kbase + r > qrow) S[qt][nt][r] = -INFINITY;
                        }
                    }
                }

                // m=0 softmax: P = exp2(S); per-lane l partials
#pragma unroll
                for (int qt = 0; qt < 4; ++qt) {
                    float s0 = 0.0f;
#pragma unroll
                    for (int nt = 0; nt < 4; ++nt)
#pragma unroll
                        for (int r = 0; r < 4; ++r) {
                            float e = __builtin_amdgcn_exp2f(S[qt][nt][r]);
                            S[qt][nt][r] = e;
                            s0 += e;
                        }
                    lp[qt] += s0;
                }

                // P: C-layout -> A-operand via per-wave swizzled LDS
#pragma unroll
                for (int qt = 0; qt < 4; ++qt) {
                    unsigned short* pw = &Pl[w][qt][0];
#pragma unroll
                    for (int nt = 0; nt < 4; ++nt) {
                        uint2 pv;
                        pv.x = pack_trunc(S[qt][nt][0], S[qt][nt][1]);
                        pv.y = pack_trunc(S[qt][nt][2], S[qt][nt][3]);
                        int chunk = (2 * nt + (qd >> 1)) ^ (l16 & 7);
                        *(uint2*)(pw + l16 * 64 + chunk * 8 + (qd & 1) * 4) = pv;
                    }
                }
                asm volatile("s_waitcnt lgkmcnt(0)" ::: "memory");

                bf16x8 pa[4][2];
#pragma unroll
                for (int qt = 0; qt < 4; ++qt)
#pragma unroll
                    for (int s = 0; s < 2; ++s)
                        pa[qt][s] = *(const bf16x8*)(&Pl[w][qt][0] + l16 * 64 +
                                                     (((s * 4 + qd) ^ (l16 & 7)) * 8));

                // V fragments (B-operand), reused across all 4 qt
                bf16x8 vf[2][4];
#pragma unroll
                for (int s = 0; s < 2; ++s)
#pragma unroll
                    for (int dh = 0; dh < 4; ++dh)
                        vf[s][dh] = *(const bf16x8*)(vl + (dh * 16 + l16) * 64 +
                                                     (((s * 4 + qd) ^ (l16 & 7)) * 8));
#pragma unroll
                for (int qt = 0; qt < 4; ++qt)
#pragma unroll
                    for (int dh = 0; dh < 4; ++dh) {
                        O[qt][dh] = __builtin_amdgcn_mfma_f32_16x16x32_bf16(pa[qt][0], vf[0][dh], O[qt][dh], 0, 0, 0);
                        O[qt][dh] = __builtin_amdgcn_mfma_f32_16x16x32_bf16(pa[qt][1], vf[1][dh], O[qt][dh], 0, 0, 0);
                    }
            }
        }

        // epilogue: reduce l across quads, normalize, store with head transpose
#pragma unroll
        for (int qt = 0; qt < 4; ++qt) {
            float lsum = lp[qt];
            lsum += __shfl_xor(lsum, 16, 64);
            lsum += __shfl_xor(lsum, 32, 64);
            float linv = 1.0f / lsum;
#pragma unroll
            for (int r = 0; r < 4; ++r) {
                float lC = __shfl(linv, qd * 4 + r, 64);
                int t = wqbase + qt * 16 + qd * 4 + r;
#pragma unroll
                for (int dh = 0; dh < 4; ++dh) {
                    size_t idx = (size_t)(b * 2048 + t) * 1024 + h * 64 + dh * 16 + l16;
                    att[idx] = f2bf(O[qt][dh][r] * lC);
                }
            }
        }
    };

    run_phase(7 - pairy);  // heavy half
    run_phase(pairy);      // light half -> uniform 36 K-steps per block
}

// ---------------------------------------------------------------------------
// Launch
// ---------------------------------------------------------------------------
extern "C" void kernel_launch(void* const* d_in, const int* in_sizes, int n_in,
                              void* d_out, int out_size, void* d_ws, size_t ws_size,
                              hipStream_t stream)
{
    const float* q = (const float*)d_in[0];
    const float* k = (const float*)d_in[1];
    const float* v = (const float*)d_in[2];
    const float* wq_w = (const float*)d_in[5];
    const float* wq_b = (const float*)d_in[6];
    const float* wk_w = (const float*)d_in[7];
    const float* wk_b = (const float*)d_in[8];
    const float* wv_w = (const float*)d_in[9];
    const float* wv_b = (const float*)d_in[10];
    const float* wo_w = (const float*)d_in[11];
    const float* wo_b = (const float*)d_in[12];

    unsigned short* ws = (unsigned short*)d_ws;
    unsigned short* att = ws;                    // 8M (attention output, bf16)
    unsigned short* wqc = ws + 25165824;         // wq,wk,wv contiguous 1M each
    unsigned short* woc = ws + 28311552;
    unsigned short* Qhp = ws + 29360128;         // Qh,Kh,Vt contiguous 8M each
    unsigned short* Khp = ws + 37748736;
    unsigned short* Vtp = ws + 46137344;

    (void)in_sizes; (void)n_in; (void)out_size; (void)ws_size;

    cast_w_kernel<<<4096, 256, 0, stream>>>(wq_w, wk_w, wv_w, wo_w, wqc);

    // fused QKV projections with in-kernel A cast; Q gets 0.125*log2(e)
    qkv_gemm_kernel<<<dim3(8, 64, 3), 256, 0, stream>>>(
        q, k, v, wqc, wq_b, wk_b, wv_b, Qhp, 0.1803368801f);

    attn_kernel<<<dim3(64, 4), 256, 0, stream>>>(Qhp, Khp, Vtp, att);

    out_gemm_kernel<<<dim3(8, 64), 256, 0, stream>>>(att, woc, wo_b, (float*)d_out);
}